// Round 1
// baseline (110.152 us; speedup 1.0000x reference)
//
#include <hip/hip_runtime.h>
#include <math.h>

#define NF 32
#define NE 64
#define NA 64
#define NP 496
#define XS 68   // padded LDS row stride (floats): 272B, 16B-aligned, spreads banks

__global__ __launch_bounds__(256, 2) void afm_fwd(
    const float* __restrict__ x,    // (B,32,64)
    const float* __restrict__ W1,   // (64,64)
    const float* __restrict__ b1,   // (64)
    const float* __restrict__ w2,   // (64,1)
    const float* __restrict__ b2,   // (1)
    float* __restrict__ out,        // (B,64)
    float* __restrict__ attn)       // (B,496)
{
    const int b    = blockIdx.x;
    const int tid  = threadIdx.x;
    const int lane = tid & 63;
    const int wv   = tid >> 6;

    __shared__ float xs[NF * XS];            // 8704 B
    __shared__ float s_l[512];               // logits -> attn weights
    __shared__ unsigned char s_r[512], s_c[512];
    __shared__ float s_red_m[4], s_red_s[4];
    __shared__ float s_acc[4][NE];

    // ---- stage x[b] into LDS (padded rows) ----
    const float* __restrict__ xb = x + (size_t)b * (NF * NE);
    for (int i = tid; i < NF * NE; i += 256) {
        xs[(i >> 6) * XS + (i & 63)] = xb[i];
    }
    // ---- pair index table (row-major triu k=1, matches np.triu_indices) ----
    for (int p = tid; p < 512; p += 256) {
        int pp = (p < NP) ? p : 0;
        int r = 0;
        while (pp >= 31 - r) { pp -= 31 - r; ++r; }
        s_r[p] = (unsigned char)r;
        s_c[p] = (unsigned char)(r + 1 + pp);
    }
    __syncthreads();

    const float bias2 = b2[0];

    // ---- phase 1: logits for all pairs. lane = pair; 8 chunks of 64 pairs ----
    for (int ck = wv; ck < 8; ck += 4) {
        const int p = (ck << 6) + lane;
        const int r = s_r[p];
        const int c = s_c[p];
        const float* xr = xs + r * XS;
        const float* xc = xs + c * XS;

        float h[NA];
        #pragma unroll
        for (int a = 0; a < NA; ++a) h[a] = b1[a];   // uniform -> SGPR

        for (int e = 0; e < NE; ++e) {
            const float ie = xr[e] * xc[e];          // 2 ds_read per 64 FMA
            const float* __restrict__ w1row = W1 + e * NA;  // uniform -> s_load
            #pragma unroll
            for (int a = 0; a < NA; ++a)
                h[a] = fmaf(ie, w1row[a], h[a]);
        }
        float logit = bias2;
        #pragma unroll
        for (int a = 0; a < NA; ++a)
            logit = fmaf(fmaxf(h[a], 0.0f), w2[a], logit);
        if (p < NP) s_l[p] = logit;
    }
    __syncthreads();

    // ---- phase 2: softmax over the 496 pair logits ----
    float m = -1e30f;
    for (int p = tid; p < NP; p += 256) m = fmaxf(m, s_l[p]);
    #pragma unroll
    for (int off = 32; off > 0; off >>= 1) m = fmaxf(m, __shfl_xor(m, off));
    if (lane == 0) s_red_m[wv] = m;
    __syncthreads();
    m = fmaxf(fmaxf(s_red_m[0], s_red_m[1]), fmaxf(s_red_m[2], s_red_m[3]));

    const float v0 = expf(s_l[tid] - m);
    const float v1 = (tid < NP - 256) ? expf(s_l[tid + 256] - m) : 0.0f;
    float sum = v0 + v1;
    #pragma unroll
    for (int off = 32; off > 0; off >>= 1) sum += __shfl_xor(sum, off);
    if (lane == 0) s_red_s[wv] = sum;
    __syncthreads();
    sum = s_red_s[0] + s_red_s[1] + s_red_s[2] + s_red_s[3];
    const float inv = 1.0f / sum;

    float* __restrict__ attn_b = attn + (size_t)b * NP;
    const float a0 = v0 * inv;
    s_l[tid] = a0;
    attn_b[tid] = a0;
    if (tid < NP - 256) {
        const float a1 = v1 * inv;
        s_l[tid + 256] = a1;
        attn_b[tid + 256] = a1;
    }
    __syncthreads();

    // ---- phase 3: out[e] = sum_p attn_p * x[r][e]*x[c][e]. lane = e ----
    float acc = 0.0f;
    for (int p = wv; p < NP; p += 4) {
        const float ap = s_l[p];                 // wave-uniform broadcast
        const int r = s_r[p];
        const int c = s_c[p];
        acc = fmaf(ap * xs[r * XS + lane], xs[c * XS + lane], acc);
    }
    s_acc[wv][lane] = acc;
    __syncthreads();
    if (tid < NE) {
        out[(size_t)b * NE + tid] =
            s_acc[0][tid] + s_acc[1][tid] + s_acc[2][tid] + s_acc[3][tid];
    }
}

extern "C" void kernel_launch(void* const* d_in, const int* in_sizes, int n_in,
                              void* d_out, int out_size, void* d_ws, size_t ws_size,
                              hipStream_t stream) {
    const float* x  = (const float*)d_in[0];
    const float* W1 = (const float*)d_in[1];
    const float* b1 = (const float*)d_in[2];
    const float* w2 = (const float*)d_in[3];
    const float* b2 = (const float*)d_in[4];

    const int B = in_sizes[0] / (NF * NE);     // 2048
    float* out_p  = (float*)d_out;             // (B,1,64) flat
    float* attn_p = (float*)d_out + (size_t)B * NE;  // (B,496,1) flat

    afm_fwd<<<B, 256, 0, stream>>>(x, W1, b1, w2, b2, out_p, attn_p);
}